// Round 5
// baseline (178.190 us; speedup 1.0000x reference)
//
#include <hip/hip_runtime.h>
#include <math.h>

#define B_ 32
#define T_ 1024
#define C_ 801
#define L_ 128
#define S_ 257            // 2*L+1
#define BLANK 800
#define RS 260            // padded emit row stride (floats); 1040B, 16B-aligned
#define NEGV -1e30f

// -------- DPP helpers --------
template <int CTRL>
__device__ __forceinline__ float dppf(float v) {
    return __uint_as_float((unsigned)__builtin_amdgcn_update_dpp(
        0, (int)__float_as_uint(v), CTRL, 0xf, 0xf, true));
}
// lane l gets lane l-1's value; lane 0 gets 0.0f   [wave_shr:1]
__device__ __forceinline__ float shift_up1(float v) { return dppf<0x138>(v); }

// full-wave max of non-negative values, broadcast to all lanes via readlane(63)
__device__ __forceinline__ float wave_max_nn(float v) {
    v = fmaxf(v, dppf<0xB1>(v));    // xor1
    v = fmaxf(v, dppf<0x4E>(v));    // xor2
    v = fmaxf(v, dppf<0x141>(v));   // row_half_mirror (xor 4)
    v = fmaxf(v, dppf<0x140>(v));   // row_mirror      (xor 8)
    v = fmaxf(v, dppf<0x142>(v));   // row_bcast15
    v = fmaxf(v, dppf<0x143>(v));   // row_bcast31
    return __uint_as_float((unsigned)__builtin_amdgcn_readlane((int)__float_as_uint(v), 63));
}
// wave reductions valid in LANE 63 only (bound_ctrl zero-fill pollutes low lanes only)
__device__ __forceinline__ float wave_red_max63(float v) {
    v = fmaxf(v, dppf<0xB1>(v));
    v = fmaxf(v, dppf<0x4E>(v));
    v = fmaxf(v, dppf<0x141>(v));
    v = fmaxf(v, dppf<0x140>(v));
    v = fmaxf(v, dppf<0x142>(v));
    v = fmaxf(v, dppf<0x143>(v));
    return v;
}
__device__ __forceinline__ float wave_red_sum63(float v) {
    v += dppf<0xB1>(v);
    v += dppf<0x4E>(v);
    v += dppf<0x141>(v);
    v += dppf<0x140>(v);
    v += dppf<0x142>(v);
    v += dppf<0x143>(v);
    return v;
}

// ================= Kernel A: fused LSE + staged linear-domain emissions =================
__global__ __launch_bounds__(320) void stage_kernel(const float* __restrict__ logits,
                                                    const int* __restrict__ labels,
                                                    const int* __restrict__ lens,
                                                    float* __restrict__ emit) {
    const int t = blockIdx.x, b = blockIdx.y;
    const float* __restrict__ x = logits + ((size_t)b * T_ + t) * C_;
    __shared__ float xs[C_];
    __shared__ float wred[5];
    __shared__ float bval;
    const int tid = threadIdx.x, lane = tid & 63, wid = tid >> 6;

    float v0 = x[tid];
    float v1 = x[tid + 320];
    float v2 = (tid < 161) ? x[tid + 640] : NEGV;
    xs[tid] = v0;
    xs[tid + 320] = v1;
    if (tid < 161) xs[tid + 640] = v2;

    float m = fmaxf(v0, fmaxf(v1, v2));
    m = wave_red_max63(m);
    if (lane == 63) wred[wid] = m;
    __syncthreads();
    if (tid == 0)
        bval = fmaxf(fmaxf(wred[0], wred[1]), fmaxf(wred[2], fmaxf(wred[3], wred[4])));
    __syncthreads();
    const float gm = bval;

    float s = __expf(v0 - gm) + __expf(v1 - gm);
    if (tid < 161) s += __expf(v2 - gm);
    s = wave_red_sum63(s);
    __syncthreads();               // everyone has read gm
    if (lane == 63) wred[wid] = s;
    __syncthreads();
    if (tid == 0) bval = gm + __logf(wred[0] + wred[1] + wred[2] + wred[3] + wred[4]);
    __syncthreads();
    const float lse = bval;

    const int ll = lens[b];
    if (tid < RS) {
        float e = 0.f;
        if (tid < S_ && tid < 2 * ll + 1) {
            int cls = (tid & 1) ? labels[b * L_ + (tid >> 1)] : BLANK;
            e = __expf(xs[cls] - lse);
        }
        emit[((size_t)b * T_ + t) * RS + tid] = e;
    }
}

// ================= Kernel B: linear CTC forward, 1 wave/batch, 31-deep named pipeline =================
// Lane l owns states 4l..4l+3 (0..255); state 256 is a scalar side-chain (real on lane 63).
__global__ __launch_bounds__(64) void ctc_lin_kernel(const float* __restrict__ emit,
                                                     const int* __restrict__ labels,
                                                     const int* __restrict__ lens,
                                                     float* __restrict__ loss) {
    const int b = blockIdx.x;
    const int lane = threadIdx.x;
    const int ll = lens[b];
    const float* __restrict__ eb = emit + (size_t)b * T_ * RS;

    // skip masks: only odd states (j=1,3) are labels
    float m21 = 0.f, m23 = 0.f;
    {
        int s1 = 4 * lane + 1;
        if (s1 >= 3) {
            int li = s1 >> 1;   // 2*lane
            m21 = (labels[b * L_ + li] != labels[b * L_ + li - 1]) ? 1.f : 0.f;
        }
        int li3 = (4 * lane + 3) >> 1;  // 2*lane+1
        m23 = (labels[b * L_ + li3] != labels[b * L_ + li3 - 1]) ? 1.f : 0.f;
    }

    // t = 0 init (emit already folds validity)
    float p0, p1, p2, p3, q;
    {
        float4 e0v = *(const float4*)(eb + 4 * lane);
        p0 = (lane == 0) ? e0v.x : 0.f;
        p1 = (lane == 0) ? e0v.y : 0.f;
        p2 = 0.f; p3 = 0.f; q = 0.f;
    }
    int E = 0;

#define STAGES(X) X(0) X(1) X(2) X(3) X(4) X(5) X(6) X(7) X(8) X(9) X(10)      \
                  X(11) X(12) X(13) X(14) X(15) X(16) X(17) X(18) X(19) X(20)  \
                  X(21) X(22) X(23) X(24) X(25) X(26) X(27) X(28) X(29) X(30)

#define DECL_STAGE(i) float4 ea##i; float eq##i;
    STAGES(DECL_STAGE)

    // eq address goes through an empty-asm VGPR constraint: hides wave-uniformity so the
    // compiler emits a VMEM load (FIFO, counted vmcnt) instead of an out-of-order SMEM load.
#define LOAD_STAGE(i, trow) {                                                  \
        const float* r_ = eb + (size_t)(trow) * RS;                            \
        ea##i = *(const float4*)(r_ + 4 * lane);                               \
        const float* rq_ = r_ + 256;                                           \
        asm("" : "+v"(rq_));                                                   \
        eq##i = *rq_; }

#define STEP(i) {                                                              \
        float shp3 = shift_up1(p3);                                            \
        float n0 = (p0 + shp3) * ea##i.x;                                      \
        float n1 = fmaf(m21, shp3, p1 + p0) * ea##i.y;                         \
        float n2 = (p2 + p1) * ea##i.z;                                        \
        float n3 = fmaf(m23, p1, p3 + p2) * ea##i.w;                           \
        q = (q + p3) * eq##i;                                                  \
        p0 = n0; p1 = n1; p2 = n2; p3 = n3; }

#define RESCALE {                                                              \
        float mx = fmaxf(fmaxf(p0, p1), fmaxf(p2, fmaxf(p3, q)));              \
        mx = wave_max_nn(mx);                                                  \
        int e2_ = (int)((__float_as_uint(mx) >> 23) & 0xFF) - 126;             \
        float sc_ = __uint_as_float((unsigned)(127 - e2_) << 23);              \
        p0 *= sc_; p1 *= sc_; p2 *= sc_; p3 *= sc_; q *= sc_;                  \
        E += e2_; }

#define INIT_STAGE(i) LOAD_STAGE(i, 1 + (i))
    STAGES(INIT_STAGE)

#define BODY(i) STEP(i) LOAD_STAGE(i, tb + 31 + (i))                           \
        if ((i) == 4 || (i) == 10 || (i) == 16 || (i) == 22 || (i) == 28) RESCALE

    for (int tb = 1; tb < T_; tb += 31) {   // 33 iterations, 1023 steps exactly
        STAGES(BODY)
    }
#undef BODY
#undef INIT_STAGE
#undef RESCALE
#undef STEP
#undef LOAD_STAGE
#undef DECL_STAGE
#undef STAGES

    __shared__ float pf[S_];
    *(float4*)(pf + 4 * lane) = make_float4(p0, p1, p2, p3);
    if (lane == 63) pf[256] = q;
    __syncthreads();
    if (lane == 0) {
        float a1 = pf[2 * ll];
        float a2 = (ll > 0) ? pf[2 * ll - 1] : 0.f;
        loss[b] = -(__logf(a1 + a2) + (float)E * 0.69314718055994531f);
    }
}

__global__ void mean_kernel(const float* __restrict__ loss, float* __restrict__ out) {
    if (threadIdx.x == 0) {
        float s = 0.f;
        for (int i = 0; i < B_; ++i) s += loss[i];
        out[0] = s / (float)B_;
    }
}

// ================= FALLBACK PATH (small ws) =================

__global__ __launch_bounds__(256) void lse_kernel(const float* __restrict__ logits,
                                                  float* __restrict__ lse) {
    const int row = blockIdx.x;
    const float* __restrict__ x = logits + (size_t)row * C_;
    const int tid = threadIdx.x, lane = tid & 63, wid = tid >> 6;
    float v0 = x[tid], v1 = x[tid + 256], v2 = x[tid + 512];
    bool h3 = (tid + 768) < C_;
    float v3 = h3 ? x[tid + 768] : NEGV;
    float m = fmaxf(fmaxf(v0, v1), fmaxf(v2, v3));
    #pragma unroll
    for (int off = 32; off > 0; off >>= 1) m = fmaxf(m, __shfl_down(m, off));
    __shared__ float wred[4]; __shared__ float bm;
    if (lane == 0) wred[wid] = m;
    __syncthreads();
    if (tid == 0) bm = fmaxf(fmaxf(wred[0], wred[1]), fmaxf(wred[2], wred[3]));
    __syncthreads();
    m = bm;
    float s = __expf(v0 - m) + __expf(v1 - m) + __expf(v2 - m);
    if (h3) s += __expf(v3 - m);
    #pragma unroll
    for (int off = 32; off > 0; off >>= 1) s += __shfl_down(s, off);
    __syncthreads();
    if (lane == 0) wred[wid] = s;
    __syncthreads();
    if (tid == 0) lse[row] = m + __logf(wred[0] + wred[1] + wred[2] + wred[3]);
}

__global__ __launch_bounds__(320) void ctc_alpha_kernel(const float* __restrict__ logits,
                                                        const int* __restrict__ labels,
                                                        const int* __restrict__ lens,
                                                        const float* __restrict__ lse,
                                                        float* __restrict__ loss) {
    const int b = blockIdx.x;
    const int s = threadIdx.x;
    const int ll = lens[b];
    __shared__ float albuf[2][S_ + 2];
    if (s < 2) { albuf[0][s] = NEGV; albuf[1][s] = NEGV; }
    int cls = BLANK; bool allow2 = false;
    if (s < S_ && (s & 1)) {
        cls = labels[b * L_ + (s >> 1)];
        allow2 = (s >= 3) && (cls != labels[b * L_ + (s >> 1) - 1]);
    }
    const bool valid = (s < 2 * ll + 1);
    const float* __restrict__ xb = logits + (size_t)b * T_ * C_;
    const float* __restrict__ lseb = lse + b * T_;
    if (s < S_) {
        float e0 = xb[cls] - lseb[0];
        float a = (s == 0 || (s == 1 && ll > 0)) ? e0 : NEGV;
        if (!valid) a = NEGV;
        albuf[0][2 + s] = a;
    }
    __syncthreads();
    float e_next = xb[(size_t)C_ + cls];
    float lse_next = lseb[1];
    int cur = 0;
    for (int t = 1; t < T_; ++t) {
        const float e = e_next, lse_t = lse_next;
        if (t + 1 < T_) { e_next = xb[(size_t)(t + 1) * C_ + cls]; lse_next = lseb[t + 1]; }
        if (s < S_) {
            float a0 = albuf[cur][2 + s];
            float a1 = albuf[cur][1 + s];
            float a2 = allow2 ? albuf[cur][s] : NEGV;
            float m = fmaxf(fmaxf(a0, a1), a2);
            float r = m + __logf(__expf(a0 - m) + __expf(a1 - m) + __expf(a2 - m)) + (e - lse_t);
            if (!valid) r = NEGV;
            albuf[cur ^ 1][2 + s] = r;
        }
        __syncthreads();
        cur ^= 1;
    }
    if (s == 0) {
        float a1 = albuf[cur][2 + 2 * ll];
        float a2 = (ll > 0) ? albuf[cur][2 + 2 * ll - 1] : NEGV;
        float m = fmaxf(a1, a2);
        loss[b] = -(m + __logf(__expf(a1 - m) + __expf(a2 - m)));
    }
}

// ================= launch =================

extern "C" void kernel_launch(void* const* d_in, const int* in_sizes, int n_in,
                              void* d_out, int out_size, void* d_ws, size_t ws_size,
                              hipStream_t stream) {
    const float* logits = (const float*)d_in[0];
    const int*   labels = (const int*)d_in[1];
    const int*   lens   = (const int*)d_in[2];
    float* out = (float*)d_out;

    const size_t emit_elems = (size_t)B_ * T_ * RS + 64 * RS;   // pad > pipeline overrun (34 rows)
    const size_t need = (emit_elems + B_) * sizeof(float);

    if (ws_size >= need) {
        float* emit = (float*)d_ws;
        float* loss = emit + emit_elems;
        dim3 grid(T_, B_);
        stage_kernel<<<grid, 320, 0, stream>>>(logits, labels, lens, emit);
        ctc_lin_kernel<<<B_, 64, 0, stream>>>(emit, labels, lens, loss);
        mean_kernel<<<1, 64, 0, stream>>>(loss, out);
    } else {
        float* lse  = (float*)d_ws;
        float* loss = lse + (size_t)B_ * T_;
        lse_kernel<<<B_ * T_, 256, 0, stream>>>(logits, lse);
        ctc_alpha_kernel<<<B_, 320, 0, stream>>>(logits, labels, lens, lse, loss);
        mean_kernel<<<1, 64, 0, stream>>>(loss, out);
    }
}

// Round 9
// 106.172 us; speedup vs baseline: 1.6783x; 1.6783x over previous
//
#include <hip/hip_runtime.h>
#include <math.h>

#define B_ 32
#define T_ 1024
#define C_ 801
#define L_ 128
#define S_ 257            // 2*L+1
#define BLANK 800
#define NEGV -1e30f

#define CH 32             // chunk rows
#define NCH (T_ / CH)     // 32 chunks

typedef const float __attribute__((address_space(1))) f32_g;
typedef float __attribute__((address_space(3))) f32_l;

// -------- DPP helpers --------
template <int CTRL>
__device__ __forceinline__ float dppf(float v) {
    return __uint_as_float((unsigned)__builtin_amdgcn_update_dpp(
        0, (int)__float_as_uint(v), CTRL, 0xf, 0xf, true));
}
// lane l gets lane l-1's value; lane 0 gets 0.0f   [wave_shr:1]
__device__ __forceinline__ float shift_up1(float v) { return dppf<0x138>(v); }

// full-wave max of non-negative values, broadcast to all lanes via readlane(63)
__device__ __forceinline__ float wave_max_nn(float v) {
    v = fmaxf(v, dppf<0xB1>(v));    // xor1
    v = fmaxf(v, dppf<0x4E>(v));    // xor2
    v = fmaxf(v, dppf<0x141>(v));   // row_half_mirror (xor 4)
    v = fmaxf(v, dppf<0x140>(v));   // row_mirror      (xor 8)
    v = fmaxf(v, dppf<0x142>(v));   // row_bcast15
    v = fmaxf(v, dppf<0x143>(v));   // row_bcast31
    return __uint_as_float((unsigned)__builtin_amdgcn_readlane((int)__float_as_uint(v), 63));
}
// wave reductions valid in LANE 63 only
__device__ __forceinline__ float wave_red_max63(float v) {
    v = fmaxf(v, dppf<0xB1>(v));
    v = fmaxf(v, dppf<0x4E>(v));
    v = fmaxf(v, dppf<0x141>(v));
    v = fmaxf(v, dppf<0x140>(v));
    v = fmaxf(v, dppf<0x142>(v));
    v = fmaxf(v, dppf<0x143>(v));
    return v;
}
__device__ __forceinline__ float wave_red_sum63(float v) {
    v += dppf<0xB1>(v);
    v += dppf<0x4E>(v);
    v += dppf<0x141>(v);
    v += dppf<0x140>(v);
    v += dppf<0x142>(v);
    v += dppf<0x143>(v);
    return v;
}

// ================= Kernel A: fused LSE + staged linear-domain emissions =================
// ea[b][t][s] for s<256 (1024B rows), eq[b][t] = state 256.
__global__ __launch_bounds__(320) void stage_kernel(const float* __restrict__ logits,
                                                    const int* __restrict__ labels,
                                                    const int* __restrict__ lens,
                                                    float* __restrict__ ea,
                                                    float* __restrict__ eq) {
    const int t = blockIdx.x, b = blockIdx.y;
    const float* __restrict__ x = logits + ((size_t)b * T_ + t) * C_;
    __shared__ float xs[C_];
    __shared__ float wred[5];
    __shared__ float bval;
    const int tid = threadIdx.x, lane = tid & 63, wid = tid >> 6;

    float v0 = x[tid];
    float v1 = x[tid + 320];
    float v2 = (tid < 161) ? x[tid + 640] : NEGV;
    xs[tid] = v0;
    xs[tid + 320] = v1;
    if (tid < 161) xs[tid + 640] = v2;

    float m = fmaxf(v0, fmaxf(v1, v2));
    m = wave_red_max63(m);
    if (lane == 63) wred[wid] = m;
    __syncthreads();
    if (tid == 0)
        bval = fmaxf(fmaxf(wred[0], wred[1]), fmaxf(wred[2], fmaxf(wred[3], wred[4])));
    __syncthreads();
    const float gm = bval;

    float s = __expf(v0 - gm) + __expf(v1 - gm);
    if (tid < 161) s += __expf(v2 - gm);
    s = wave_red_sum63(s);
    __syncthreads();               // everyone has read gm
    if (lane == 63) wred[wid] = s;
    __syncthreads();
    if (tid == 0) bval = gm + __logf(wred[0] + wred[1] + wred[2] + wred[3] + wred[4]);
    __syncthreads();
    const float lse = bval;

    const int ll = lens[b];
    const int row = b * T_ + t;
    if (tid < 256) {
        float e = 0.f;
        if (tid < 2 * ll + 1) {
            int cls = (tid & 1) ? labels[b * L_ + (tid >> 1)] : BLANK;
            e = __expf(xs[cls] - lse);
        }
        ea[(size_t)row * 256 + tid] = e;
    } else if (tid == 256) {
        float e = (256 < 2 * ll + 1) ? __expf(xs[BLANK] - lse) : 0.f;
        eq[row] = e;
    }
}

// ================= Kernel B helpers =================

__device__ __forceinline__ void stage_chunk(const float* gbase, int c, float* lbase, int lane) {
    #pragma unroll
    for (int j = 0; j < CH; ++j) {
        const float* gp = gbase + ((size_t)(c * CH + j)) * 256 + 4 * lane;  // per-lane 16B
        float* lp = lbase + j * 256;                                        // wave-uniform base
        __builtin_amdgcn_global_load_lds((f32_g*)gp, (f32_l*)lp, 16, 0, 0);
    }
}

template <int J0>
__device__ __forceinline__ void compute_chunk(const float* bufp, float eqc, int lane,
                                              float m21, float m23,
                                              float& p0, float& p1, float& p2, float& p3,
                                              float& q, int& E) {
    #pragma unroll
    for (int j = J0; j < CH; ++j) {
        float4 ev = *(const float4*)(bufp + j * 256 + 4 * lane);   // ds_read_b128
        float eqt = __uint_as_float(
            (unsigned)__builtin_amdgcn_readlane((int)__float_as_uint(eqc), j));
        float shp3 = shift_up1(p3);
        float n0 = (p0 + shp3) * ev.x;
        float n1 = fmaf(m21, shp3, p1 + p0) * ev.y;
        float n2 = (p2 + p1) * ev.z;
        float n3 = fmaf(m23, p1, p3 + p2) * ev.w;
        q = (q + p3) * eqt;
        p0 = n0; p1 = n1; p2 = n2; p3 = n3;
        if ((j & 7) == 7) {   // rescale every 8 steps: decay >= 0.007^8 ~ 2e-18, safe
            float mx = fmaxf(fmaxf(p0, p1), fmaxf(p2, fmaxf(p3, q)));
            mx = wave_max_nn(mx);
            int e2_ = (int)((__float_as_uint(mx) >> 23) & 0xFF) - 126;
            float sc_ = __uint_as_float((unsigned)(127 - e2_) << 23);
            p0 *= sc_; p1 *= sc_; p2 *= sc_; p3 *= sc_; q *= sc_;
            E += e2_;
        }
    }
}

// ================= Kernel B: linear CTC forward, 1 wave/batch, LDS double-buffered =================
// Lane l owns states 4l..4l+3; state 256 is a scalar side-chain (real on lane 63).
// ONLY fence: __syncthreads() (compiler-understood; drains vmcnt+lgkmcnt).
__global__ __launch_bounds__(64) void ctc_lds_kernel(const float* __restrict__ ea,
                                                     const float* __restrict__ eqg,
                                                     const int* __restrict__ labels,
                                                     const int* __restrict__ lens,
                                                     float* __restrict__ loss) {
    __shared__ float buf[2][CH * 256];   // 2 x 32 KB = 64 KB exactly
    const int b = blockIdx.x;
    const int lane = threadIdx.x;
    const int ll = lens[b];
    const float* gbase = ea + (size_t)b * T_ * 256;
    const float* qbase = eqg + b * T_;

    // skip masks: only odd states (slots 1,3) are labels
    float m21 = 0.f, m23 = 0.f;
    {
        int s1 = 4 * lane + 1;
        if (s1 >= 3) {
            int li = s1 >> 1;   // 2*lane
            m21 = (labels[b * L_ + li] != labels[b * L_ + li - 1]) ? 1.f : 0.f;
        }
        int li3 = (4 * lane + 3) >> 1;  // 2*lane+1
        m23 = (labels[b * L_ + li3] != labels[b * L_ + li3 - 1]) ? 1.f : 0.f;
    }

    // prologue: stage chunk 0; barrier completes it
    stage_chunk(gbase, 0, buf[0], lane);
    float eqC = qbase[lane & 31];        // chunk-0 eq rows in lanes 0..31
    __syncthreads();

    float p0, p1, p2, p3, q;
    {
        float4 r0 = *(const float4*)(buf[0] + 4 * lane);
        p0 = (lane == 0) ? r0.x : 0.f;
        p1 = (lane == 0) ? r0.y : 0.f;
        p2 = 0.f; p3 = 0.f; q = 0.f;
    }
    int E = 0;
    float eqN = 0.f;

    #pragma unroll 1
    for (int c = 0; c < NCH; ++c) {
        // issue next chunk's DMA into the other buffer, then compute this chunk;
        // the end-of-iteration barrier drains the DMA after compute covered its latency.
        if (c + 1 < NCH) {
            stage_chunk(gbase, c + 1, buf[(c + 1) & 1], lane);
            eqN = qbase[(c + 1) * CH + (lane & 31)];
        }
        if (c == 0) compute_chunk<1>(buf[0],       eqC, lane, m21, m23, p0, p1, p2, p3, q, E);
        else        compute_chunk<0>(buf[c & 1],   eqC, lane, m21, m23, p0, p1, p2, p3, q, E);
        eqC = eqN;
        __syncthreads();
    }

    // termination: reuse buf[0] row 0..1 as the gather scratch
    *(float4*)(buf[0] + 4 * lane) = make_float4(p0, p1, p2, p3);
    if (lane == 63) buf[0][256] = q;
    __syncthreads();
    if (lane == 0) {
        float a1 = buf[0][2 * ll];
        float a2 = (ll > 0) ? buf[0][2 * ll - 1] : 0.f;
        loss[b] = -(__logf(a1 + a2) + (float)E * 0.69314718055994531f);
    }
}

__global__ void mean_kernel(const float* __restrict__ loss, float* __restrict__ out) {
    if (threadIdx.x == 0) {
        float s = 0.f;
        for (int i = 0; i < B_; ++i) s += loss[i];
        out[0] = s / (float)B_;
    }
}

// ================= FALLBACK PATH (small ws) =================

__global__ __launch_bounds__(256) void lse_kernel(const float* __restrict__ logits,
                                                  float* __restrict__ lse) {
    const int row = blockIdx.x;
    const float* __restrict__ x = logits + (size_t)row * C_;
    const int tid = threadIdx.x, lane = tid & 63, wid = tid >> 6;
    float v0 = x[tid], v1 = x[tid + 256], v2 = x[tid + 512];
    bool h3 = (tid + 768) < C_;
    float v3 = h3 ? x[tid + 768] : NEGV;
    float m = fmaxf(fmaxf(v0, v1), fmaxf(v2, v3));
    #pragma unroll
    for (int off = 32; off > 0; off >>= 1) m = fmaxf(m, __shfl_down(m, off));
    __shared__ float wred[4]; __shared__ float bm;
    if (lane == 0) wred[wid] = m;
    __syncthreads();
    if (tid == 0) bm = fmaxf(fmaxf(wred[0], wred[1]), fmaxf(wred[2], wred[3]));
    __syncthreads();
    m = bm;
    float s = __expf(v0 - m) + __expf(v1 - m) + __expf(v2 - m);
    if (h3) s += __expf(v3 - m);
    #pragma unroll
    for (int off = 32; off > 0; off >>= 1) s += __shfl_down(s, off);
    __syncthreads();
    if (lane == 0) wred[wid] = s;
    __syncthreads();
    if (tid == 0) lse[row] = m + __logf(wred[0] + wred[1] + wred[2] + wred[3]);
}

__global__ __launch_bounds__(320) void ctc_alpha_kernel(const float* __restrict__ logits,
                                                        const int* __restrict__ labels,
                                                        const int* __restrict__ lens,
                                                        const float* __restrict__ lse,
                                                        float* __restrict__ loss) {
    const int b = blockIdx.x;
    const int s = threadIdx.x;
    const int ll = lens[b];
    __shared__ float albuf[2][S_ + 2];
    if (s < 2) { albuf[0][s] = NEGV; albuf[1][s] = NEGV; }
    int cls = BLANK; bool allow2 = false;
    if (s < S_ && (s & 1)) {
        cls = labels[b * L_ + (s >> 1)];
        allow2 = (s >= 3) && (cls != labels[b * L_ + (s >> 1) - 1]);
    }
    const bool valid = (s < 2 * ll + 1);
    const float* __restrict__ xb = logits + (size_t)b * T_ * C_;
    const float* __restrict__ lseb = lse + b * T_;
    if (s < S_) {
        float e0 = xb[cls] - lseb[0];
        float a = (s == 0 || (s == 1 && ll > 0)) ? e0 : NEGV;
        if (!valid) a = NEGV;
        albuf[0][2 + s] = a;
    }
    __syncthreads();
    float e_next = xb[(size_t)C_ + cls];
    float lse_next = lseb[1];
    int cur = 0;
    for (int t = 1; t < T_; ++t) {
        const float e = e_next, lse_t = lse_next;
        if (t + 1 < T_) { e_next = xb[(size_t)(t + 1) * C_ + cls]; lse_next = lseb[t + 1]; }
        if (s < S_) {
            float a0 = albuf[cur][2 + s];
            float a1 = albuf[cur][1 + s];
            float a2 = allow2 ? albuf[cur][s] : NEGV;
            float m = fmaxf(fmaxf(a0, a1), a2);
            float r = m + __logf(__expf(a0 - m) + __expf(a1 - m) + __expf(a2 - m)) + (e - lse_t);
            if (!valid) r = NEGV;
            albuf[cur ^ 1][2 + s] = r;
        }
        __syncthreads();
        cur ^= 1;
    }
    if (s == 0) {
        float a1 = albuf[cur][2 + 2 * ll];
        float a2 = (ll > 0) ? albuf[cur][2 + 2 * ll - 1] : NEGV;
        float m = fmaxf(a1, a2);
        loss[b] = -(m + __logf(__expf(a1 - m) + __expf(a2 - m)));
    }
}

// ================= launch =================

extern "C" void kernel_launch(void* const* d_in, const int* in_sizes, int n_in,
                              void* d_out, int out_size, void* d_ws, size_t ws_size,
                              hipStream_t stream) {
    const float* logits = (const float*)d_in[0];
    const int*   labels = (const int*)d_in[1];
    const int*   lens   = (const int*)d_in[2];
    float* out = (float*)d_out;

    const size_t ea_elems = (size_t)B_ * T_ * 256;
    const size_t eq_elems = (size_t)B_ * T_;
    const size_t need = (ea_elems + eq_elems + B_) * sizeof(float);

    if (ws_size >= need) {
        float* ea   = (float*)d_ws;
        float* eq   = ea + ea_elems;
        float* loss = eq + eq_elems;
        dim3 grid(T_, B_);
        stage_kernel<<<grid, 320, 0, stream>>>(logits, labels, lens, ea, eq);
        ctc_lds_kernel<<<B_, 64, 0, stream>>>(ea, eq, labels, lens, loss);
        mean_kernel<<<1, 64, 0, stream>>>(loss, out);
    } else {
        float* lse  = (float*)d_ws;
        float* loss = lse + (size_t)B_ * T_;
        lse_kernel<<<B_ * T_, 256, 0, stream>>>(logits, lse);
        ctc_alpha_kernel<<<B_, 320, 0, stream>>>(logits, labels, lens, lse, loss);
        mean_kernel<<<1, 64, 0, stream>>>(loss, out);
    }
}